// Round 11
// baseline (349.689 us; speedup 1.0000x reference)
//
#include <hip/hip_runtime.h>
#include <math.h>

typedef unsigned short u16;
typedef __attribute__((ext_vector_type(8))) short short8;     // 8 bf16 = one MFMA A/B frag
typedef __attribute__((ext_vector_type(4))) float floatx4;    // MFMA C/D frag
typedef __attribute__((ext_vector_type(4))) unsigned short ushort4v;

// ---------- bf16 helpers (raw u16, RNE) ----------
__device__ __forceinline__ u16 f2bf(float f) {
    union { float f; unsigned int u; } v; v.f = f;
    unsigned int r = v.u + 0x7fffu + ((v.u >> 16) & 1u);
    return (u16)(r >> 16);
}
__device__ __forceinline__ unsigned int pk2bf(float a, float b) {
#if __has_builtin(__builtin_amdgcn_cvt_pk_bf16_f32)
    auto r = __builtin_amdgcn_cvt_pk_bf16_f32(a, b);
    union { decltype(r) v; unsigned int u; } cv; cv.v = r; return cv.u;
#else
    return (unsigned int)f2bf(a) | ((unsigned int)f2bf(b) << 16);
#endif
}
// bare v_exp_f32 (no OCML range-fixup wrapper); inputs bounded in this kernel
__device__ __forceinline__ float fexp2(float x) {
#if __has_builtin(__builtin_amdgcn_exp2f)
    return __builtin_amdgcn_exp2f(x);
#else
    return exp2f(x);
#endif
}

// ---------- cross-lane reg-bit <-> lane-bit swaps ----------
__device__ __forceinline__ void swap32(unsigned int& x0, unsigned int& x1, int lane) {
#if __has_builtin(__builtin_amdgcn_permlane32_swap)
    (void)lane;
    auto r = __builtin_amdgcn_permlane32_swap((int)x0, (int)x1, false, false);
    x0 = (unsigned int)r[0]; x1 = (unsigned int)r[1];
#else
    const bool hi = (lane & 32) != 0;
    const unsigned int s = hi ? x0 : x1;
    const unsigned int rr = (unsigned int)__shfl_xor((int)s, 32, 64);
    const unsigned int n0 = hi ? rr : x0;
    const unsigned int n1 = hi ? x1 : rr;
    x0 = n0; x1 = n1;
#endif
}
__device__ __forceinline__ void swap16(unsigned int& x0, unsigned int& x1, int lane) {
#if __has_builtin(__builtin_amdgcn_permlane16_swap)
    (void)lane;
    auto r = __builtin_amdgcn_permlane16_swap((int)x0, (int)x1, false, false);
    x0 = (unsigned int)r[0]; x1 = (unsigned int)r[1];
#else
    const bool hi = (lane & 16) != 0;
    const unsigned int s = hi ? x0 : x1;
    const unsigned int rr = (unsigned int)__shfl_xor((int)s, 16, 64);
    const unsigned int n0 = hi ? rr : x0;
    const unsigned int n1 = hi ? x1 : rr;
    x0 = n0; x1 = n1;
#endif
}

// async global -> LDS, 16B per lane (dst must be linear: wave base + lane*16)
__device__ __forceinline__ void g2l16(const u16* g, u16* l) {
    __builtin_amdgcn_global_load_lds(
        (const __attribute__((address_space(1))) void*)g,
        (__attribute__((address_space(3))) void*)l, 16, 0, 0);
}

// =====================================================================
// wfuse: w_z[row] = dot(W_z[row][:], wv_z[:]) ; block x==0 also emits
// bdot[z] = dot(bl_z, wv_z).  grid (64, 4).
// =====================================================================
struct WFuseJobs { const float* W[4]; const float* wv[4]; const float* bl[4];
                   float* out[4]; float* bdot; };

__global__ __launch_bounds__(256) void wfuse(WFuseJobs wf) {
    const int z = blockIdx.y;
    const float* W = wf.W[z];
    const float* wv = wf.wv[z];
    float* out = wf.out[z];
    const int t = threadIdx.x;
    const int lane = t & 63, w = t >> 6;
#pragma unroll
    for (int i = 0; i < 4; i++) {
        const int row = blockIdx.x * 16 + w * 4 + i;
        const float* Wr = W + (size_t)row * 1024 + lane * 16;
        const float* vr = wv + lane * 16;
        float p = 0.f;
#pragma unroll
        for (int c = 0; c < 4; c++) {
            const floatx4 a = *(const floatx4*)(Wr + c * 4);
            const floatx4 b = *(const floatx4*)(vr + c * 4);
            p += a[0] * b[0] + a[1] * b[1] + a[2] * b[2] + a[3] * b[3];
        }
#pragma unroll
        for (int m = 1; m <= 32; m <<= 1) p += __shfl_xor(p, m);
        if (lane == 0) out[row] = p;
    }
    if (blockIdx.x == 0) {
        const floatx4 bb = *(const floatx4*)(wf.bl[z] + t * 4);
        const floatx4 vv = *(const floatx4*)(wv + t * 4);
        float p = bb[0] * vv[0] + bb[1] * vv[1] + bb[2] * vv[2] + bb[3] * vv[3];
#pragma unroll
        for (int m = 1; m <= 32; m <<= 1) p += __shfl_xor(p, m);
        __shared__ float red[4];
        if ((t & 63) == 0) red[t >> 6] = p;
        __syncthreads();
        if (t == 0) wf.bdot[z] = red[0] + red[1] + red[2] + red[3];
    }
}

// =====================================================================
// gatewt: fused gatecast (z=0..2) + weight-transpose (z=3..8).
// grid (1024, 9), block 256.
// =====================================================================
struct GCWJobs {
    const float* xa[3]; const float* xc[3];
    const float* w1[3]; const float* w2[3];
    const float* bdot;                 // 4 scalars
    const float* sA[3]; const float* sB[3];
    float* lamout[3];
    u16* dst[3];
    const float* wsrc[6]; u16* wdst[6]; int wstride[6]; int wkoff[6];
};

__global__ __launch_bounds__(256) void gatewt(GCWJobs gj) {
    __shared__ float tile[32][33];
    const int z = blockIdx.y;
    const int t = threadIdx.x;

    if (z >= 3) {                       // ---- wtrans job z-3 ----
        const int j = z - 3;
        const float* W = gj.wsrc[j];
        u16* Wt = gj.wdst[j];
        const int stride = gj.wstride[j], koff = gj.wkoff[j];
        const int n0 = (blockIdx.x & 31) * 32, k0 = (blockIdx.x >> 5) * 32;
        const int tx = t & 31, ty = t >> 5;
#pragma unroll
        for (int i = 0; i < 4; i++)
            tile[ty + i * 8][tx] = W[(size_t)(k0 + ty + i * 8) * 1024 + n0 + tx];
        __syncthreads();
#pragma unroll
        for (int i = 0; i < 4; i++)
            Wt[(size_t)(n0 + ty + i * 8) * stride + koff + k0 + tx] = f2bf(tile[tx][ty + i * 8]);
        return;
    }

    const int lane = t & 63, w = t >> 6;
    const int row = blockIdx.x * 4 + w;
    const int e0 = lane * 4;

    if (z == 2) {                       // ---- v cast ----
#pragma unroll
        for (int c = 0; c < 4; c++) {
            const floatx4 a = *(const floatx4*)(gj.xa[2] + (size_t)row * 1024 + c * 256 + e0);
            ushort4v o;
            const unsigned int lo = pk2bf(a[0], a[1]);
            const unsigned int hi = pk2bf(a[2], a[3]);
            o[0] = (u16)(lo & 0xffff); o[1] = (u16)(lo >> 16);
            o[2] = (u16)(hi & 0xffff); o[3] = (u16)(hi >> 16);
            *(ushort4v*)(gj.dst[2] + (size_t)row * 1024 + c * 256 + e0) = o;
        }
        return;
    }

    floatx4 av[4], cv[4];
    float p = 0.f;
#pragma unroll
    for (int c = 0; c < 4; c++) {
        av[c] = *(const floatx4*)(gj.xa[z] + (size_t)row * 1024 + c * 256 + e0);
        cv[c] = *(const floatx4*)(gj.xc[z] + (size_t)row * 1024 + c * 256 + e0);
        const floatx4 w1 = *(const floatx4*)(gj.w1[z] + c * 256 + e0);
        const floatx4 w2 = *(const floatx4*)(gj.w2[z] + c * 256 + e0);
#pragma unroll
        for (int j = 0; j < 4; j++) p += av[c][j] * w1[j] + cv[c][j] * w2[j];
    }
#pragma unroll
    for (int m = 1; m <= 32; m <<= 1) p += __shfl_xor(p, m);
    const float x = p + gj.bdot[2 * z] + gj.bdot[2 * z + 1]
                  + gj.sA[z][0] + gj.sB[z][0];
    const float lam = 1.f / (1.f + exp2f(-x * 1.44269504f));
    if (lane == 0) gj.lamout[z][row] = lam;
    const float oml = 1.f - lam;

    u16* d = gj.dst[z] + (size_t)row * 2048;
#pragma unroll
    for (int c = 0; c < 4; c++) {
        ushort4v o1, o2;
        {
            const unsigned int lo = pk2bf(oml * av[c][0], oml * av[c][1]);
            const unsigned int hi = pk2bf(oml * av[c][2], oml * av[c][3]);
            o1[0] = (u16)(lo & 0xffff); o1[1] = (u16)(lo >> 16);
            o1[2] = (u16)(hi & 0xffff); o1[3] = (u16)(hi >> 16);
        }
        {
            const unsigned int lo = pk2bf(lam * cv[c][0], lam * cv[c][1]);
            const unsigned int hi = pk2bf(lam * cv[c][2], lam * cv[c][3]);
            o2[0] = (u16)(lo & 0xffff); o2[1] = (u16)(lo >> 16);
            o2[2] = (u16)(hi & 0xffff); o2[3] = (u16)(hi >> 16);
        }
        *(ushort4v*)(d + c * 256 + e0) = o1;
        *(ushort4v*)(d + 1024 + c * 256 + e0) = o2;
    }
}

// =====================================================================
// transpose V: V[s][base+d] (stride 2048) -> Vtg[(bh*64+d)*2048 + s], bf16
// =====================================================================
__global__ __launch_bounds__(256) void vtrans(const u16* __restrict__ V,
                                              u16* __restrict__ Vtg) {
    __shared__ u16 tile[32][34];
    const int bh = blockIdx.z, b = bh >> 4, h = bh & 15;
    const int base = b * 1024 + h * 64;
    const int s0 = blockIdx.x * 32, d0 = blockIdx.y * 32;
    const int tx = threadIdx.x & 31, ty = threadIdx.x >> 5;
#pragma unroll
    for (int i = 0; i < 4; i++)
        tile[ty + i * 8][tx] = V[(size_t)(s0 + ty + i * 8) * 2048 + base + d0 + tx];
    __syncthreads();
#pragma unroll
    for (int i = 0; i < 4; i++)
        Vtg[((size_t)bh * 64 + d0 + ty + i * 8) * 2048 + s0 + tx] = tile[tx][ty + i * 8];
}

// =====================================================================
// shared GEMM job descriptor
// =====================================================================
struct PJob {
    const u16* A; const u16* Bt; int K;
    const float* biasA; const float* biasC; const float* lam;
    u16* out; float* outf; float scale;
};
struct PJobs { PJob j[4]; };

// =====================================================================
// proj256p: 256x256 tile, BK=32, 512 threads (8 waves 2M x 4N), 4 LDS
// buffers (128 KB) -> TRUE prefetch distance 3 with counted vmcnt (T4):
// per K-step: s_waitcnt vmcnt(8) (tile t's 4 loads done; tiles t+1,t+2's
// 8 loads STAY IN FLIGHT across the barrier) -> s_barrier -> issue
// stage(t+3) -> 12 ds_read + 32 MFMA (setprio-wrapped).
// Ledger: prologue stages tiles 0,1,2 (12 loads). At tile t: outstanding
// = tiles t..min(t+2,nt-1); wait leaves min(2, nt-1-t) tiles in flight
// (N = 8 / 4 / 0). WAR: stage(t+3) overwrites buf[(t-1)&3], whose reads
// all completed before the tile-t barrier. Cross-wave RAW: wait-then-
// barrier makes every wave's loads complete before any wave reads.
// Swizzle (conflict-free at BK=32): unit ^= (row>>1)&3 on BOTH the g2l
// source and the ds_read offset -> 16-lane read spreads 2-way (free).
// Epilogue/geometry identical to the round-5-verified 256^2 kernel.
// grid 192 blocks (4,16,3), XCD-bijective (192 = 8*24).
// =====================================================================
__global__ __launch_bounds__(512, 2) void proj256p(PJobs jobs) {
    __shared__ __align__(16) u16 As[4][256 * 32];   // 64 KB
    __shared__ __align__(16) u16 Bs[4][256 * 32];   // 64 KB

    const int bid = blockIdx.x + 4 * (blockIdx.y + 16 * blockIdx.z); // 0..191
    const int sw = (bid & 7) * 24 + (bid >> 3);                      // bijective
    const PJob jb = jobs.j[sw >> 6];
    const int r = sw & 63;
    const int m0 = (r >> 2) * 256;
    const int n0 = (r & 3) * 256;
    const int K = jb.K;

    const int t = threadIdx.x;
    const int lane = t & 63;
    const int wv = t >> 6;                 // 0..7
    const int wm = wv >> 2, wn = wv & 3;   // 2M x 4N, wave tile 128x64
    const int qd = lane >> 4, lm = lane & 15;

    const floatx4 zero4 = {0.f, 0.f, 0.f, 0.f};
    floatx4 acc[8][4];
#pragma unroll
    for (int i = 0; i < 8; i++)
#pragma unroll
        for (int j = 0; j < 4; j++) acc[i][j] = zero4;

    // staging: thread t -> row t>>2 (0..127) (+128 for 2nd load), unit t&3.
    // source unit pre-swizzled: su = (t&3) ^ s(row), s(row) = (row>>1)&3 =
    // (t>>3)&3 (unchanged by +128). LDS dst linear: t*8 u16 (+4096).
    const int srow = t >> 2;
    const int su = (t & 3) ^ ((t >> 3) & 3);
    const u16* Ap = jb.A + (size_t)(m0 + srow) * K + su * 8;
    const u16* Bp = jb.Bt + (size_t)(n0 + srow) * K + su * 8;

#define STG(BUF, KO) do {                                              \
        g2l16(Ap + (KO),                   &As[BUF][t * 8]);           \
        g2l16(Ap + (KO) + (size_t)128 * K, &As[BUF][4096 + t * 8]);    \
        g2l16(Bp + (KO),                   &Bs[BUF][t * 8]);           \
        g2l16(Bp + (KO) + (size_t)128 * K, &Bs[BUF][4096 + t * 8]);    \
    } while (0)

    // read offset (u16): row*32 + (qd ^ ((lm>>1)&3))*8  (s(row)=(lm>>1)&3
    // since all row-base terms are multiples of 16)
    const int ua = (qd ^ ((lm >> 1) & 3)) << 3;
    const int aBase = (wm * 128 + lm) * 32 + ua;
    const int bBase = (wn * 64 + lm) * 32 + ua;

    const int nt = K >> 5;                 // 64 (q,k) or 32 (v)
    STG(0, 0);
    STG(1, 32);
    STG(2, 64);

#pragma unroll 1
    for (int kt = 0; kt < nt; kt++) {
        const int rem = nt - 1 - kt;
        if (rem >= 2)      asm volatile("s_waitcnt vmcnt(8)" ::: "memory");
        else if (rem == 1) asm volatile("s_waitcnt vmcnt(4)" ::: "memory");
        else               asm volatile("s_waitcnt vmcnt(0)" ::: "memory");
        __builtin_amdgcn_s_barrier();
        if (kt + 3 < nt) {
            STG((kt + 3) & 3, (kt + 3) * 32);
        }

        const int buf = kt & 3;
        const u16* Ab = &As[buf][0];
        const u16* Bb = &Bs[buf][0];

        short8 bfr[4];
#pragma unroll
        for (int j = 0; j < 4; j++)
            bfr[j] = *(const short8*)&Bb[bBase + j * 16 * 32];
#pragma unroll
        for (int i = 0; i < 8; i++) {
            const short8 af = *(const short8*)&Ab[aBase + i * 16 * 32];
            __builtin_amdgcn_s_setprio(1);
#pragma unroll
            for (int j = 0; j < 4; j++)
                acc[i][j] = __builtin_amdgcn_mfma_f32_16x16x32_bf16(af, bfr[j], acc[i][j], 0, 0, 0);
            __builtin_amdgcn_s_setprio(0);
        }
    }
#undef STG

    // epilogue (round-5-verified mapping)
#pragma unroll
    for (int i = 0; i < 8; i++) {
        const int mb = m0 + wm * 128 + i * 16 + qd * 4;
        float lamv[4];
        if (jb.lam) {
#pragma unroll
            for (int rr = 0; rr < 4; rr++) lamv[rr] = jb.lam[mb + rr];
        }
#pragma unroll
        for (int j = 0; j < 4; j++) {
            const int col = n0 + wn * 64 + j * 16 + lm;
            const float bA = jb.biasA[col];
            if (jb.outf) {
#pragma unroll
                for (int rr = 0; rr < 4; rr++)
                    jb.outf[(size_t)(mb + rr) * 1024 + col] = acc[i][j][rr] + bA;
            } else if (jb.lam) {
                const float dB = jb.biasC[col] - bA;
#pragma unroll
                for (int rr = 0; rr < 4; rr++)
                    jb.out[(size_t)(mb + rr) * 1024 + col] =
                        f2bf((acc[i][j][rr] + bA + lamv[rr] * dB) * jb.scale);
            } else {
#pragma unroll
                for (int rr = 0; rr < 4; rr++)
                    jb.out[(size_t)(mb + rr) * 1024 + col] =
                        f2bf((acc[i][j][rr] + bA) * jb.scale);
            }
        }
    }
}

// =====================================================================
// projout: output projection, 128x64 tile -> 512 blocks = 2/CU.
// =====================================================================
__global__ __launch_bounds__(256, 2) void projout(const u16* __restrict__ A,
                                                  const u16* __restrict__ Bt,
                                                  const float* __restrict__ bias,
                                                  float* __restrict__ C) {
    __shared__ __align__(16) u16 As[2][128 * 32];
    __shared__ __align__(16) u16 Bs[2][64 * 32];
    const int K = 1024;
    const int bid = blockIdx.x;                    // 512
    const int sw = (bid & 7) * 64 + (bid >> 3);    // XCD bijective (512%8==0)
    const int m0 = (sw >> 4) * 128;                // 32 m-tiles
    const int n0 = (sw & 15) * 64;                 // 16 n-tiles
    const int t = threadIdx.x;
    const int lane = t & 63;
    const int wid = t >> 6;
    const int wm = wid >> 1, wn = wid & 1;
    const int qd = lane >> 4, lm = lane & 15;

    const floatx4 zero4 = {0.f, 0.f, 0.f, 0.f};
    floatx4 acc[4][2];
#pragma unroll
    for (int i = 0; i < 4; i++)
#pragma unroll
        for (int j2 = 0; j2 < 2; j2++) acc[i][j2] = zero4;

    const int srow = t >> 2;                 // 0..63
    const int su = (t & 3) ^ (srow & 3);
    const u16* Ap = A + (size_t)(m0 + srow) * K + su * 8;
    const u16* Bp = Bt + (size_t)(n0 + srow) * K + su * 8;

#define OSTG(BUF, KOFF) do {                                           \
        g2l16(Ap + (KOFF),                   &As[BUF][t * 8]);         \
        g2l16(Ap + (KOFF) + (size_t)64 * K,  &As[BUF][2048 + t * 8]);  \
        g2l16(Bp + (KOFF),                   &Bs[BUF][t * 8]);         \
    } while (0)

    OSTG(0, 0);
    __syncthreads();
    int cur = 0;
    const int ua = (qd ^ (lm & 3)) << 3;
    for (int k0 = 0; k0 < K; k0 += 32) {
        if (k0 + 32 < K) OSTG(cur ^ 1, k0 + 32);

        short8 af[4], bfg[2];
#pragma unroll
        for (int i = 0; i < 4; i++)
            af[i] = *(const short8*)&As[cur][(wm * 64 + i * 16 + lm) * 32 + ua];
#pragma unroll
        for (int j2 = 0; j2 < 2; j2++)
            bfg[j2] = *(const short8*)&Bs[cur][(wn * 32 + j2 * 16 + lm) * 32 + ua];
#pragma unroll
        for (int i = 0; i < 4; i++)
#pragma unroll
            for (int j2 = 0; j2 < 2; j2++)
                acc[i][j2] = __builtin_amdgcn_mfma_f32_16x16x32_bf16(af[i], bfg[j2], acc[i][j2], 0, 0, 0);

        __syncthreads();
        cur ^= 1;
    }
#undef OSTG

#pragma unroll
    for (int i = 0; i < 4; i++) {
        const int mb = m0 + wm * 64 + i * 16 + qd * 4;
#pragma unroll
        for (int j2 = 0; j2 < 2; j2++) {
            const int col = n0 + wn * 32 + j2 * 16 + lm;
            const float bv = bias[col];
#pragma unroll
            for (int r = 0; r < 4; r++)
                C[(size_t)(mb + r) * 1024 + col] = acc[i][j2][r] + bv;
        }
    }
}

// =====================================================================
// attention v8: full-KV per block, 8 waves / 512 threads / 128 q-rows.
// grid (16, 32) = 512 blocks = 2/CU. Direct bf16 ctx/l write (no merge).
// =====================================================================
__global__ __launch_bounds__(512, 2) void attn8(
    const u16* __restrict__ Q, const u16* __restrict__ Kk,
    const u16* __restrict__ Vtg, u16* __restrict__ ctxbf) {
    __shared__ __align__(16) u16 SB[16384];   // [2 bufs][K 64x64 | V 64x64] bf16

    const int bid = blockIdx.x + 16 * blockIdx.y;   // 512
    const int sw = (bid & 7) * 64 + (bid >> 3);     // XCD bijective (512%8==0)
    const int qt = sw & 15;                          // 16 q-tiles of 128 rows
    const int bh = sw >> 4;                          // 4 bh per XCD chunk
    const int b = bh >> 4, h = bh & 15;
    const int hb = b * 1024 + h * 64;

    const int t = threadIdx.x, lane = t & 63, w = t >> 6;   // w = 0..7
    const int qd = lane >> 4, lm = lane & 15;
    const int q0w = qt * 128 + w * 16;

    // Q fragments (B operand of swapped QK^T): 16 rows/wave, 2 k-chunks
    short8 qf[2];
    {
        const u16* qr = Q + (size_t)(q0w + lm) * 2048 + hb;
        qf[0] = *(const short8*)(qr + qd * 8);
        qf[1] = *(const short8*)(qr + 32 + qd * 8);
    }

    const floatx4 zero4 = {0.f, 0.f, 0.f, 0.f};
    floatx4 ctx[4];
#pragma unroll
    for (int g = 0; g < 4; g++) ctx[g] = zero4;
    floatx4 accL = zero4;

    // all-ones bf16 B fragment for the denominator MFMA
    union { unsigned int u[4]; short8 s; } ov;
    ov.u[0] = ov.u[1] = ov.u[2] = ov.u[3] = 0x3F803F80u;
    const short8 onesb = ov.s;

    // staging: 512 threads cover one 64x64 tile per matrix: thread t ->
    // row rl = t>>3 (0..63), 16B-unit t&7, source unit pre-swizzled.
    const int rl = t >> 3;                  // 0..63
    const int cuz = (t & 7) ^ (rl & 7);     // swizzled source 16B-unit
    const u16* kp = Kk + (size_t)rl * 2048 + hb + cuz * 8;
    const u16* vp = Vtg + ((size_t)bh * 64 + rl) * 2048 + cuz * 8;
    u16* kd = &SB[t * 8];                   // rl*64 + (t&7)*8 == t*8
    u16* vd = &SB[4096 + t * 8];

    // swizzled LDS read offsets (u16 units)
    const int rdA = lm * 64 + ((qd ^ (lm & 7)) << 3);
    const int rdB = rdA ^ 32;

#define STAGE(BUF) do {                                             \
        g2l16(kp, kd + (BUF) * 8192);                               \
        g2l16(vp, vd + (BUF) * 8192);                               \
        kp += 64 * 2048; vp += 64;                                  \
    } while (0)

#define COMPUTE(BUF) do {                                                          \
        short8 pa[2];                                                              \
        _Pragma("unroll")                                                          \
        for (int gp = 0; gp < 2; gp++) {                                           \
            unsigned int pw[2][2];                                                 \
            _Pragma("unroll")                                                      \
            for (int g0 = 0; g0 < 2; g0++) {                                       \
                const int g = gp * 2 + g0;                                         \
                const short8 kf0 = *(const short8*)&SB[(BUF) * 8192 + g * 1024 + rdA]; \
                const short8 kf1 = *(const short8*)&SB[(BUF) * 8192 + g * 1024 + rdB]; \
                floatx4 st = zero4;                                                \
                st = __builtin_amdgcn_mfma_f32_16x16x32_bf16(kf0, qf[0], st, 0, 0, 0); \
                st = __builtin_amdgcn_mfma_f32_16x16x32_bf16(kf1, qf[1], st, 0, 0, 0); \
                const float e0 = fexp2(st[0]), e1 = fexp2(st[1]);                  \
                const float e2 = fexp2(st[2]), e3 = fexp2(st[3]);                  \
                pw[g0][0] = pk2bf(e0, e1);                                         \
                pw[g0][1] = pk2bf(e2, e3);                                         \
            }                                                                      \
            unsigned int a0 = pw[0][0], b0 = pw[1][0];                             \
            unsigned int a1 = pw[0][1], b1 = pw[1][1];                             \
            swap32(a0, b0, lane); swap32(a1, b1, lane);                            \
            swap16(a0, b0, lane); swap16(a1, b1, lane);                            \
            union { unsigned int u[4]; short8 s; } cvv;                            \
            cvv.u[0] = a0; cvv.u[1] = a1; cvv.u[2] = b0; cvv.u[3] = b1;            \
            pa[gp] = cvv.s;                                                        \
        }                                                                          \
        __builtin_amdgcn_s_setprio(1);                                             \
        _Pragma("unroll")                                                          \
        for (int g = 0; g < 4; g++) {                                              \
            const short8 vb0 = *(const short8*)&SB[(BUF) * 8192 + 4096 + g * 1024 + rdA]; \
            const short8 vb1 = *(const short8*)&SB[(BUF) * 8192 + 4096 + g * 1024 + rdB]; \
            ctx[g] = __builtin_amdgcn_mfma_f32_16x16x32_bf16(pa[0], vb0, ctx[g], 0, 0, 0); \
            ctx[g] = __builtin_amdgcn_mfma_f32_16x16x32_bf16(pa[1], vb1, ctx[g], 0, 0, 0); \
        }                                                                          \
        accL = __builtin_amdgcn_mfma_f32_16x16x32_bf16(pa[0], onesb, accL, 0, 0, 0); \
        accL = __builtin_amdgcn_mfma_f32_16x16x32_bf16(pa[1], onesb, accL, 0, 0, 0); \
        __builtin_amdgcn_s_setprio(0);                                             \
    } while (0)

    STAGE(0);   // prologue: tile 0 -> buf0
#pragma unroll 1
    for (int it = 0; it < 16; it++) {
        __syncthreads();            // buf0 ready (vmcnt drained); buf1 reads done
        STAGE(1);                   // prefetch tile 2*it+1 -> buf1
        COMPUTE(0);                 // tile 2*it from buf0
        __syncthreads();            // buf1 ready; buf0 reads done
        if (it < 15) STAGE(0);      // prefetch tile 2*it+2 -> buf0
        COMPUTE(1);                 // tile 2*it+1 from buf1
    }
#undef STAGE
#undef COMPUTE

    // epilogue: full denominator known -> write ctx/l as bf16 directly
#pragma unroll
    for (int r = 0; r < 4; r++) {
        const float inv = 1.0f / accL[r];
        const int srow = q0w + qd * 4 + r;
        u16* orow = ctxbf + (size_t)srow * 2048 + hb;
#pragma unroll
        for (int g = 0; g < 4; g++)
            orow[g * 16 + lm] = f2bf(ctx[g][r] * inv);
    }
}

// =====================================================================
// host orchestration (6 launches)
// =====================================================================
extern "C" void kernel_launch(void* const* d_in, const int* in_sizes, int n_in,
                              void* d_out, int out_size, void* d_ws, size_t ws_size,
                              hipStream_t stream) {
    const float* qx = (const float*)d_in[0];
    const float* kx = (const float*)d_in[1];
    const float* vx = (const float*)d_in[2];
    const float* qc = (const float*)d_in[3];
    const float* kc = (const float*)d_in[4];
    const float* W_qx = (const float*)d_in[5];   const float* b_qx = (const float*)d_in[6];
    const float* W_kx = (const float*)d_in[7];   const float* b_kx = (const float*)d_in[8];
    const float* W_vx = (const float*)d_in[9];   const float* b_vx = (const float*)d_in[10];
    const float* W_qc = (const float*)d_in[11];  const float* b_qc = (const float*)d_in[12];
    const float* W_kc = (const float*)d_in[13];  const float* b_kc = (const float*)d_in[14];
    const float* W_out = (const float*)d_in[15]; const float* b_out = (const float*)d_in[16];
    const float* W_Vqx = (const float*)d_in[17]; const float* b_Vqx = (const float*)d_in[18];
    const float* W_Vqc = (const float*)d_in[19]; const float* b_Vqc = (const float*)d_in[20];
    const float* W_Vkx = (const float*)d_in[21]; const float* b_Vkx = (const float*)d_in[22];
    const float* W_Vkc = (const float*)d_in[23]; const float* b_Vkc = (const float*)d_in[24];

    char* ws = (char*)d_ws;
    const size_t MB = 1048576;
    u16* Aq  = (u16*)ws;
    u16* Ak  = (u16*)(ws + 16 * MB);
    u16* Av  = (u16*)(ws + 32 * MB);
    u16* Wtq = (u16*)(ws + 40 * MB);
    u16* Wtk = (u16*)(ws + 44 * MB);
    u16* Wtv = (u16*)(ws + 48 * MB);
    u16* Wto = (u16*)(ws + 50 * MB);
    u16* Pv    = (u16*)(ws + 52 * MB);
    u16* qg    = (u16*)(ws + 60 * MB);
    u16* kg    = (u16*)(ws + 68 * MB);
    u16* ctxbf = (u16*)(ws + 76 * MB);
    float* wfused = (float*)(ws + 84 * MB);                       // 4 x 1024
    float* bdot   = (float*)(ws + 84 * MB + 16384);               // 4 scalars
    float* lam    = (float*)(ws + 84 * MB + 16384 + 256);         // 2 x 4096
    u16* Vtg    = (u16*)(ws + 32 * MB);        // aliases Av (dead after proj)

    // 1. fused gating weight vectors + bias-dot consts
    WFuseJobs wf;
    wf.W[0] = W_qx; wf.wv[0] = W_Vqx; wf.bl[0] = b_qx; wf.out[0] = wfused;
    wf.W[1] = W_qc; wf.wv[1] = W_Vqc; wf.bl[1] = b_qc; wf.out[1] = wfused + 1024;
    wf.W[2] = W_kx; wf.wv[2] = W_Vkx; wf.bl[2] = b_kx; wf.out[2] = wfused + 2048;
    wf.W[3] = W_kc; wf.wv[3] = W_Vkc; wf.bl[3] = b_kc; wf.out[3] = wfused + 3072;
    wf.bdot = bdot;
    wfuse<<<dim3(64, 4), 256, 0, stream>>>(wf);

    // 2. gatewt: lambdas + scaled concat-K bf16 A matrices + v cast
    //    + all 6 weight transposes, one launch.
    GCWJobs gj;
    gj.xa[0] = qx; gj.xc[0] = qc; gj.w1[0] = wfused;        gj.w2[0] = wfused + 1024;
    gj.sA[0] = b_Vqx; gj.sB[0] = b_Vqc; gj.lamout[0] = lam;        gj.dst[0] = Aq;
    gj.xa[1] = kx; gj.xc[1] = kc; gj.w1[1] = wfused + 2048; gj.w2[1] = wfused + 3072;
    gj.sA[1] = b_Vkx; gj.sB[1] = b_Vkc; gj.lamout[1] = lam + 4096; gj.dst[1] = Ak;
    gj.xa[2] = vx; gj.xc[2] = nullptr; gj.w1[2] = nullptr; gj.w2[2] = nullptr;
    gj.sA[2] = nullptr; gj.sB[2] = nullptr; gj.lamout[2] = nullptr; gj.dst[2] = Av;
    gj.bdot = bdot;
    gj.wsrc[0] = W_qx; gj.wdst[0] = Wtq; gj.wstride[0] = 2048; gj.wkoff[0] = 0;
    gj.wsrc[1] = W_qc; gj.wdst[1] = Wtq; gj.wstride[1] = 2048; gj.wkoff[1] = 1024;
    gj.wsrc[2] = W_kx; gj.wdst[2] = Wtk; gj.wstride[2] = 2048; gj.wkoff[2] = 0;
    gj.wsrc[3] = W_kc; gj.wdst[3] = Wtk; gj.wstride[3] = 2048; gj.wkoff[3] = 1024;
    gj.wsrc[4] = W_vx; gj.wdst[4] = Wtv; gj.wstride[4] = 1024; gj.wkoff[4] = 0;
    gj.wsrc[5] = W_out; gj.wdst[5] = Wto; gj.wstride[5] = 1024; gj.wkoff[5] = 0;
    gatewt<<<dim3(1024, 9), 256, 0, stream>>>(gj);

    // 3. projections via proj256p: q (K=2048, pre-scaled), k (K=2048),
    //    v (K=1024). grid (4,16,3) = 192 blocks, counted-vmcnt pipeline.
    const float QSCALE = 0.18033688011112042f;   // log2(e)/sqrt(64)
    PJobs pj;
    pj.j[0].A = Aq; pj.j[0].Bt = Wtq; pj.j[0].K = 2048;
    pj.j[0].biasA = b_qx; pj.j[0].biasC = b_qc; pj.j[0].lam = lam;
    pj.j[0].out = qg; pj.j[0].outf = nullptr; pj.j[0].scale = QSCALE;
    pj.j[1].A = Ak; pj.j[1].Bt = Wtk; pj.j[1].K = 2048;
    pj.j[1].biasA = b_kx; pj.j[1].biasC = b_kc; pj.j[1].lam = lam + 4096;
    pj.j[1].out = kg; pj.j[1].outf = nullptr; pj.j[1].scale = 1.0f;
    pj.j[2].A = Av; pj.j[2].Bt = Wtv; pj.j[2].K = 1024;
    pj.j[2].biasA = b_vx; pj.j[2].biasC = nullptr; pj.j[2].lam = nullptr;
    pj.j[2].out = Pv; pj.j[2].outf = nullptr; pj.j[2].scale = 1.0f;
    pj.j[3] = pj.j[2];
    proj256p<<<dim3(4, 16, 3), 512, 0, stream>>>(pj);

    // 4. transpose V (Av dead -> Vtg aliases it)
    vtrans<<<dim3(64, 2, 32), 256, 0, stream>>>(Pv, Vtg);

    // 5. attention (full KV, 128 q-rows/block, 8 waves, direct bf16 write)
    attn8<<<dim3(16, 32), 512, 0, stream>>>(qg, kg, Vtg, ctxbf);

    // 6. output projection -> d_out (fp32): 128x64 tiles, 512 blocks
    projout<<<dim3(512), 256, 0, stream>>>(ctxbf, Wto, b_out, (float*)d_out);
}

// Round 12
// 321.122 us; speedup vs baseline: 1.0890x; 1.0890x over previous
//
#include <hip/hip_runtime.h>
#include <math.h>

typedef unsigned short u16;
typedef __attribute__((ext_vector_type(8))) short short8;     // 8 bf16 = one MFMA A/B frag
typedef __attribute__((ext_vector_type(4))) float floatx4;    // MFMA C/D frag
typedef __attribute__((ext_vector_type(4))) unsigned short ushort4v;

// ---------- bf16 helpers (raw u16, RNE) ----------
__device__ __forceinline__ u16 f2bf(float f) {
    union { float f; unsigned int u; } v; v.f = f;
    unsigned int r = v.u + 0x7fffu + ((v.u >> 16) & 1u);
    return (u16)(r >> 16);
}
__device__ __forceinline__ unsigned int pk2bf(float a, float b) {
#if __has_builtin(__builtin_amdgcn_cvt_pk_bf16_f32)
    auto r = __builtin_amdgcn_cvt_pk_bf16_f32(a, b);
    union { decltype(r) v; unsigned int u; } cv; cv.v = r; return cv.u;
#else
    return (unsigned int)f2bf(a) | ((unsigned int)f2bf(b) << 16);
#endif
}
// bare v_exp_f32 (no OCML range-fixup wrapper); inputs bounded in this kernel
__device__ __forceinline__ float fexp2(float x) {
#if __has_builtin(__builtin_amdgcn_exp2f)
    return __builtin_amdgcn_exp2f(x);
#else
    return exp2f(x);
#endif
}

// ---------- cross-lane reg-bit <-> lane-bit swaps ----------
__device__ __forceinline__ void swap32(unsigned int& x0, unsigned int& x1, int lane) {
#if __has_builtin(__builtin_amdgcn_permlane32_swap)
    (void)lane;
    auto r = __builtin_amdgcn_permlane32_swap((int)x0, (int)x1, false, false);
    x0 = (unsigned int)r[0]; x1 = (unsigned int)r[1];
#else
    const bool hi = (lane & 32) != 0;
    const unsigned int s = hi ? x0 : x1;
    const unsigned int rr = (unsigned int)__shfl_xor((int)s, 32, 64);
    const unsigned int n0 = hi ? rr : x0;
    const unsigned int n1 = hi ? x1 : rr;
    x0 = n0; x1 = n1;
#endif
}
__device__ __forceinline__ void swap16(unsigned int& x0, unsigned int& x1, int lane) {
#if __has_builtin(__builtin_amdgcn_permlane16_swap)
    (void)lane;
    auto r = __builtin_amdgcn_permlane16_swap((int)x0, (int)x1, false, false);
    x0 = (unsigned int)r[0]; x1 = (unsigned int)r[1];
#else
    const bool hi = (lane & 16) != 0;
    const unsigned int s = hi ? x0 : x1;
    const unsigned int rr = (unsigned int)__shfl_xor((int)s, 16, 64);
    const unsigned int n0 = hi ? rr : x0;
    const unsigned int n1 = hi ? x1 : rr;
    x0 = n0; x1 = n1;
#endif
}

// async global -> LDS, 16B per lane (dst must be linear: wave base + lane*16)
__device__ __forceinline__ void g2l16(const u16* g, u16* l) {
    __builtin_amdgcn_global_load_lds(
        (const __attribute__((address_space(1))) void*)g,
        (__attribute__((address_space(3))) void*)l, 16, 0, 0);
}

// =====================================================================
// wfuse: w_z[row] = dot(W_z[row][:], wv_z[:]) ; block x==0 also emits
// bdot[z] = dot(bl_z, wv_z).  grid (64, 4).
// =====================================================================
struct WFuseJobs { const float* W[4]; const float* wv[4]; const float* bl[4];
                   float* out[4]; float* bdot; };

__global__ __launch_bounds__(256) void wfuse(WFuseJobs wf) {
    const int z = blockIdx.y;
    const float* W = wf.W[z];
    const float* wv = wf.wv[z];
    float* out = wf.out[z];
    const int t = threadIdx.x;
    const int lane = t & 63, w = t >> 6;
#pragma unroll
    for (int i = 0; i < 4; i++) {
        const int row = blockIdx.x * 16 + w * 4 + i;
        const float* Wr = W + (size_t)row * 1024 + lane * 16;
        const float* vr = wv + lane * 16;
        float p = 0.f;
#pragma unroll
        for (int c = 0; c < 4; c++) {
            const floatx4 a = *(const floatx4*)(Wr + c * 4);
            const floatx4 b = *(const floatx4*)(vr + c * 4);
            p += a[0] * b[0] + a[1] * b[1] + a[2] * b[2] + a[3] * b[3];
        }
#pragma unroll
        for (int m = 1; m <= 32; m <<= 1) p += __shfl_xor(p, m);
        if (lane == 0) out[row] = p;
    }
    if (blockIdx.x == 0) {
        const floatx4 bb = *(const floatx4*)(wf.bl[z] + t * 4);
        const floatx4 vv = *(const floatx4*)(wv + t * 4);
        float p = bb[0] * vv[0] + bb[1] * vv[1] + bb[2] * vv[2] + bb[3] * vv[3];
#pragma unroll
        for (int m = 1; m <= 32; m <<= 1) p += __shfl_xor(p, m);
        __shared__ float red[4];
        if ((t & 63) == 0) red[t >> 6] = p;
        __syncthreads();
        if (t == 0) wf.bdot[z] = red[0] + red[1] + red[2] + red[3];
    }
}

// =====================================================================
// gatewt: fused gatecast (z=0..2) + weight-transpose (z=3..8).
// grid (1024, 9), block 256.
// =====================================================================
struct GCWJobs {
    const float* xa[3]; const float* xc[3];
    const float* w1[3]; const float* w2[3];
    const float* bdot;                 // 4 scalars
    const float* sA[3]; const float* sB[3];
    float* lamout[3];
    u16* dst[3];
    const float* wsrc[6]; u16* wdst[6]; int wstride[6]; int wkoff[6];
};

__global__ __launch_bounds__(256) void gatewt(GCWJobs gj) {
    __shared__ float tile[32][33];
    const int z = blockIdx.y;
    const int t = threadIdx.x;

    if (z >= 3) {                       // ---- wtrans job z-3 ----
        const int j = z - 3;
        const float* W = gj.wsrc[j];
        u16* Wt = gj.wdst[j];
        const int stride = gj.wstride[j], koff = gj.wkoff[j];
        const int n0 = (blockIdx.x & 31) * 32, k0 = (blockIdx.x >> 5) * 32;
        const int tx = t & 31, ty = t >> 5;
#pragma unroll
        for (int i = 0; i < 4; i++)
            tile[ty + i * 8][tx] = W[(size_t)(k0 + ty + i * 8) * 1024 + n0 + tx];
        __syncthreads();
#pragma unroll
        for (int i = 0; i < 4; i++)
            Wt[(size_t)(n0 + ty + i * 8) * stride + koff + k0 + tx] = f2bf(tile[tx][ty + i * 8]);
        return;
    }

    const int lane = t & 63, w = t >> 6;
    const int row = blockIdx.x * 4 + w;
    const int e0 = lane * 4;

    if (z == 2) {                       // ---- v cast ----
#pragma unroll
        for (int c = 0; c < 4; c++) {
            const floatx4 a = *(const floatx4*)(gj.xa[2] + (size_t)row * 1024 + c * 256 + e0);
            ushort4v o;
            const unsigned int lo = pk2bf(a[0], a[1]);
            const unsigned int hi = pk2bf(a[2], a[3]);
            o[0] = (u16)(lo & 0xffff); o[1] = (u16)(lo >> 16);
            o[2] = (u16)(hi & 0xffff); o[3] = (u16)(hi >> 16);
            *(ushort4v*)(gj.dst[2] + (size_t)row * 1024 + c * 256 + e0) = o;
        }
        return;
    }

    floatx4 av[4], cv[4];
    float p = 0.f;
#pragma unroll
    for (int c = 0; c < 4; c++) {
        av[c] = *(const floatx4*)(gj.xa[z] + (size_t)row * 1024 + c * 256 + e0);
        cv[c] = *(const floatx4*)(gj.xc[z] + (size_t)row * 1024 + c * 256 + e0);
        const floatx4 w1 = *(const floatx4*)(gj.w1[z] + c * 256 + e0);
        const floatx4 w2 = *(const floatx4*)(gj.w2[z] + c * 256 + e0);
#pragma unroll
        for (int j = 0; j < 4; j++) p += av[c][j] * w1[j] + cv[c][j] * w2[j];
    }
#pragma unroll
    for (int m = 1; m <= 32; m <<= 1) p += __shfl_xor(p, m);
    const float x = p + gj.bdot[2 * z] + gj.bdot[2 * z + 1]
                  + gj.sA[z][0] + gj.sB[z][0];
    const float lam = 1.f / (1.f + exp2f(-x * 1.44269504f));
    if (lane == 0) gj.lamout[z][row] = lam;
    const float oml = 1.f - lam;

    u16* d = gj.dst[z] + (size_t)row * 2048;
#pragma unroll
    for (int c = 0; c < 4; c++) {
        ushort4v o1, o2;
        {
            const unsigned int lo = pk2bf(oml * av[c][0], oml * av[c][1]);
            const unsigned int hi = pk2bf(oml * av[c][2], oml * av[c][3]);
            o1[0] = (u16)(lo & 0xffff); o1[1] = (u16)(lo >> 16);
            o1[2] = (u16)(hi & 0xffff); o1[3] = (u16)(hi >> 16);
        }
        {
            const unsigned int lo = pk2bf(lam * cv[c][0], lam * cv[c][1]);
            const unsigned int hi = pk2bf(lam * cv[c][2], lam * cv[c][3]);
            o2[0] = (u16)(lo & 0xffff); o2[1] = (u16)(lo >> 16);
            o2[2] = (u16)(hi & 0xffff); o2[3] = (u16)(hi >> 16);
        }
        *(ushort4v*)(d + c * 256 + e0) = o1;
        *(ushort4v*)(d + 1024 + c * 256 + e0) = o2;
    }
}

// =====================================================================
// transpose V: V[s][base+d] (stride 2048) -> Vtg[(bh*64+d)*2048 + s], bf16
// =====================================================================
__global__ __launch_bounds__(256) void vtrans(const u16* __restrict__ V,
                                              u16* __restrict__ Vtg) {
    __shared__ u16 tile[32][34];
    const int bh = blockIdx.z, b = bh >> 4, h = bh & 15;
    const int base = b * 1024 + h * 64;
    const int s0 = blockIdx.x * 32, d0 = blockIdx.y * 32;
    const int tx = threadIdx.x & 31, ty = threadIdx.x >> 5;
#pragma unroll
    for (int i = 0; i < 4; i++)
        tile[ty + i * 8][tx] = V[(size_t)(s0 + ty + i * 8) * 2048 + base + d0 + tx];
    __syncthreads();
#pragma unroll
    for (int i = 0; i < 4; i++)
        Vtg[((size_t)bh * 64 + d0 + ty + i * 8) * 2048 + s0 + tx] = tile[tx][ty + i * 8];
}

// =====================================================================
// shared GEMM job descriptor
// =====================================================================
struct PJob {
    const u16* A; const u16* Bt; int K;
    const float* biasA; const float* biasC; const float* lam;
    u16* out; float* outf; float scale;
};
struct PJobs { PJob j[4]; };

// =====================================================================
// projall v5 (128x128, BK=32, proven 70.5us): global_load_lds pipeline +
// XCD-colocated grid + LDS unit swizzle. ONE barrier per K-step.
// (256^2 variants tried twice -- both fill-limited at this shape.)
// =====================================================================
__global__ __launch_bounds__(256, 3) void projall(PJobs jobs) {
    __shared__ __align__(16) u16 As[2][128 * 32];
    __shared__ __align__(16) u16 Bs[2][128 * 32];
    const int nj = gridDim.z;
    const int bid = blockIdx.x + 8 * (blockIdx.y + 32 * blockIdx.z);
    const int sw = (bid & 7) * (32 * nj) + (bid >> 3);
    const PJob jb = jobs.j[sw >> 8];
    const int K = jb.K;
    const int m0 = ((sw >> 3) & 31) * 128;
    const int n0 = (sw & 7) * 128;
    const int t = threadIdx.x;
    const int lane = t & 63;
    const int wid = t >> 6;
    const int wm = wid >> 1, wn = wid & 1;
    const int qd = lane >> 4, lm = lane & 15;

    const floatx4 zero4 = {0.f, 0.f, 0.f, 0.f};
    floatx4 acc[4][4];
#pragma unroll
    for (int i = 0; i < 4; i++)
#pragma unroll
        for (int j2 = 0; j2 < 4; j2++) acc[i][j2] = zero4;

    const int srow = t >> 2;
    const int su = (t & 3) ^ (srow & 3);
    const u16* Ap = jb.A + (size_t)(m0 + srow) * K + su * 8;
    const u16* Bp = jb.Bt + (size_t)(n0 + srow) * K + su * 8;

#define PSTAGE(BUF, KOFF) do {                                         \
        g2l16(Ap + (KOFF),                   &As[BUF][t * 8]);         \
        g2l16(Ap + (KOFF) + (size_t)64 * K,  &As[BUF][2048 + t * 8]);  \
        g2l16(Bp + (KOFF),                   &Bs[BUF][t * 8]);         \
        g2l16(Bp + (KOFF) + (size_t)64 * K,  &Bs[BUF][2048 + t * 8]);  \
    } while (0)

    PSTAGE(0, 0);
    __syncthreads();
    int cur = 0;
    const int ua = (qd ^ (lm & 3)) << 3;
    for (int k0 = 0; k0 < K; k0 += 32) {
        if (k0 + 32 < K) PSTAGE(cur ^ 1, k0 + 32);

        short8 af[4], bfg[4];
#pragma unroll
        for (int i = 0; i < 4; i++) {
            af[i]  = *(const short8*)&As[cur][(wm * 64 + i * 16 + lm) * 32 + ua];
            bfg[i] = *(const short8*)&Bs[cur][(wn * 64 + i * 16 + lm) * 32 + ua];
        }
#pragma unroll
        for (int i = 0; i < 4; i++)
#pragma unroll
            for (int j2 = 0; j2 < 4; j2++)
                acc[i][j2] = __builtin_amdgcn_mfma_f32_16x16x32_bf16(af[i], bfg[j2], acc[i][j2], 0, 0, 0);

        __syncthreads();
        cur ^= 1;
    }
#undef PSTAGE

#pragma unroll
    for (int i = 0; i < 4; i++) {
        const int mb = m0 + wm * 64 + i * 16 + qd * 4;
        float lamv[4];
        if (jb.lam) {
#pragma unroll
            for (int r = 0; r < 4; r++) lamv[r] = jb.lam[mb + r];
        }
#pragma unroll
        for (int j2 = 0; j2 < 4; j2++) {
            const int col = n0 + wn * 64 + j2 * 16 + lm;
            const float bA = jb.biasA[col];
            if (jb.outf) {
#pragma unroll
                for (int r = 0; r < 4; r++)
                    jb.outf[(size_t)(mb + r) * 1024 + col] = acc[i][j2][r] + bA;
            } else if (jb.lam) {
                const float dB = jb.biasC[col] - bA;
#pragma unroll
                for (int r = 0; r < 4; r++)
                    jb.out[(size_t)(mb + r) * 1024 + col] =
                        f2bf((acc[i][j2][r] + bA + lamv[r] * dB) * jb.scale);
            } else {
#pragma unroll
                for (int r = 0; r < 4; r++)
                    jb.out[(size_t)(mb + r) * 1024 + col] =
                        f2bf((acc[i][j2][r] + bA) * jb.scale);
            }
        }
    }
}

// =====================================================================
// projout: output projection, 128x64 tile -> 512 blocks = 2/CU.
// =====================================================================
__global__ __launch_bounds__(256, 2) void projout(const u16* __restrict__ A,
                                                  const u16* __restrict__ Bt,
                                                  const float* __restrict__ bias,
                                                  float* __restrict__ C) {
    __shared__ __align__(16) u16 As[2][128 * 32];
    __shared__ __align__(16) u16 Bs[2][64 * 32];
    const int K = 1024;
    const int bid = blockIdx.x;                    // 512
    const int sw = (bid & 7) * 64 + (bid >> 3);    // XCD bijective (512%8==0)
    const int m0 = (sw >> 4) * 128;                // 32 m-tiles
    const int n0 = (sw & 15) * 64;                 // 16 n-tiles
    const int t = threadIdx.x;
    const int lane = t & 63;
    const int wid = t >> 6;
    const int wm = wid >> 1, wn = wid & 1;
    const int qd = lane >> 4, lm = lane & 15;

    const floatx4 zero4 = {0.f, 0.f, 0.f, 0.f};
    floatx4 acc[4][2];
#pragma unroll
    for (int i = 0; i < 4; i++)
#pragma unroll
        for (int j2 = 0; j2 < 2; j2++) acc[i][j2] = zero4;

    const int srow = t >> 2;                 // 0..63
    const int su = (t & 3) ^ (srow & 3);
    const u16* Ap = A + (size_t)(m0 + srow) * K + su * 8;
    const u16* Bp = Bt + (size_t)(n0 + srow) * K + su * 8;

#define OSTG(BUF, KOFF) do {                                           \
        g2l16(Ap + (KOFF),                   &As[BUF][t * 8]);         \
        g2l16(Ap + (KOFF) + (size_t)64 * K,  &As[BUF][2048 + t * 8]);  \
        g2l16(Bp + (KOFF),                   &Bs[BUF][t * 8]);         \
    } while (0)

    OSTG(0, 0);
    __syncthreads();
    int cur = 0;
    const int ua = (qd ^ (lm & 3)) << 3;
    for (int k0 = 0; k0 < K; k0 += 32) {
        if (k0 + 32 < K) OSTG(cur ^ 1, k0 + 32);

        short8 af[4], bfg[2];
#pragma unroll
        for (int i = 0; i < 4; i++)
            af[i] = *(const short8*)&As[cur][(wm * 64 + i * 16 + lm) * 32 + ua];
#pragma unroll
        for (int j2 = 0; j2 < 2; j2++)
            bfg[j2] = *(const short8*)&Bs[cur][(wn * 32 + j2 * 16 + lm) * 32 + ua];
#pragma unroll
        for (int i = 0; i < 4; i++)
#pragma unroll
            for (int j2 = 0; j2 < 2; j2++)
                acc[i][j2] = __builtin_amdgcn_mfma_f32_16x16x32_bf16(af[i], bfg[j2], acc[i][j2], 0, 0, 0);

        __syncthreads();
        cur ^= 1;
    }
#undef OSTG

#pragma unroll
    for (int i = 0; i < 4; i++) {
        const int mb = m0 + wm * 64 + i * 16 + qd * 4;
#pragma unroll
        for (int j2 = 0; j2 < 2; j2++) {
            const int col = n0 + wn * 32 + j2 * 16 + lm;
            const float bv = bias[col];
#pragma unroll
            for (int r = 0; r < 4; r++)
                C[(size_t)(mb + r) * 1024 + col] = acc[i][j2][r] + bv;
        }
    }
}

// =====================================================================
// attention v9: full-KV per block, 4 waves x 32 q-rows (qh=2) = 128
// q-rows/block. grid (16, 32) = 512 blocks. Combines:
//  - attn6's qh=2 COMPUTE (proven rounds 2-7): 16 ds_read per 32 useful
//    MFMA (0.5 reads/MFMA vs attn8's 0.75) -> per-CU LDS reads drop 33%.
//  - attn8's staging amortization: 512 KB KV per block over 128 q-rows
//    (total staged 256 MB).
//  - direct bf16 ctx/l write (no merge kernel, no fp32 partials).
// =====================================================================
__global__ __launch_bounds__(256, 2) void attn9(
    const u16* __restrict__ Q, const u16* __restrict__ Kk,
    const u16* __restrict__ Vtg, u16* __restrict__ ctxbf) {
    __shared__ __align__(16) u16 SB[16384];   // [2 bufs][K 64x64 | V 64x64] bf16

    const int bid = blockIdx.x + 16 * blockIdx.y;   // 512
    const int sw = (bid & 7) * 64 + (bid >> 3);     // XCD bijective (512%8==0)
    const int qt = sw & 15;                          // 16 q-tiles of 128 rows
    const int bh = sw >> 4;                          // 4 bh per XCD chunk
    const int b = bh >> 4, h = bh & 15;
    const int hb = b * 1024 + h * 64;

    const int t = threadIdx.x, lane = t & 63, w = t >> 6;   // w = 0..3
    const int qd = lane >> 4, lm = lane & 15;
    const int q0w = qt * 128 + w * 32;

    // Q fragments (B operand of swapped QK^T): 2 qh blocks x 2 k-chunks
    short8 qf[2][2];
#pragma unroll
    for (int qh = 0; qh < 2; qh++) {
        const u16* qr = Q + (size_t)(q0w + qh * 16 + lm) * 2048 + hb;
#pragma unroll
        for (int c = 0; c < 2; c++)
            qf[qh][c] = *(const short8*)(qr + c * 32 + qd * 8);
    }

    const floatx4 zero4 = {0.f, 0.f, 0.f, 0.f};
    floatx4 ctx[2][4];
#pragma unroll
    for (int qh = 0; qh < 2; qh++)
#pragma unroll
        for (int g = 0; g < 4; g++) ctx[qh][g] = zero4;
    floatx4 accL[2] = {zero4, zero4};

    // all-ones bf16 B fragment for the denominator MFMA
    union { unsigned int u[4]; short8 s; } ov;
    ov.u[0] = ov.u[1] = ov.u[2] = ov.u[3] = 0x3F803F80u;
    const short8 onesb = ov.s;

    // staging (attn6's proven pattern): wave w stages K kv-rows w*16.. and
    // V d-rows w*16.. ; source 16B-unit pre-swizzled: unit ^ (row&7).
    const int rl = lane >> 3;               // 0..7
    const int cuz = (lane & 7) ^ rl;        // swizzled source 16B-unit
    const u16* kp = Kk + (size_t)(w * 16 + rl) * 2048 + hb + cuz * 8;
    const u16* vp = Vtg + ((size_t)bh * 64 + w * 16 + rl) * 2048 + cuz * 8;
    u16* kd = &SB[(w * 16) * 64];
    u16* vd = &SB[4096 + (w * 16) * 64];

    // swizzled LDS read offsets (u16 units)
    const int rdA = lm * 64 + ((qd ^ (lm & 7)) << 3);
    const int rdB = rdA ^ 32;

#define STAGE(BUF) do {                                             \
        g2l16(kp,            kd + (BUF) * 8192);                    \
        g2l16(kp + 8 * 2048, kd + (BUF) * 8192 + 8 * 64);           \
        g2l16(vp,            vd + (BUF) * 8192);                    \
        g2l16(vp + 8 * 2048, vd + (BUF) * 8192 + 8 * 64);           \
        kp += 64 * 2048; vp += 64;                                  \
    } while (0)

#define COMPUTE(BUF) do {                                                          \
        short8 pa[2][2];                                                           \
        _Pragma("unroll")                                                          \
        for (int gp = 0; gp < 2; gp++) {                                           \
            unsigned int pw[2][2][2];                                              \
            _Pragma("unroll")                                                      \
            for (int g0 = 0; g0 < 2; g0++) {                                       \
                const int g = gp * 2 + g0;                                         \
                const short8 kf0 = *(const short8*)&SB[(BUF) * 8192 + g * 1024 + rdA]; \
                const short8 kf1 = *(const short8*)&SB[(BUF) * 8192 + g * 1024 + rdB]; \
                _Pragma("unroll")                                                  \
                for (int qh = 0; qh < 2; qh++) {                                   \
                    floatx4 st = zero4;                                            \
                    st = __builtin_amdgcn_mfma_f32_16x16x32_bf16(kf0, qf[qh][0], st, 0, 0, 0); \
                    st = __builtin_amdgcn_mfma_f32_16x16x32_bf16(kf1, qf[qh][1], st, 0, 0, 0); \
                    const float e0 = fexp2(st[0]), e1 = fexp2(st[1]);              \
                    const float e2 = fexp2(st[2]), e3 = fexp2(st[3]);              \
                    pw[qh][g0][0] = pk2bf(e0, e1);                                 \
                    pw[qh][g0][1] = pk2bf(e2, e3);                                 \
                }                                                                  \
            }                                                                      \
            _Pragma("unroll")                                                      \
            for (int qh = 0; qh < 2; qh++) {                                       \
                unsigned int a0 = pw[qh][0][0], b0 = pw[qh][1][0];                 \
                unsigned int a1 = pw[qh][0][1], b1 = pw[qh][1][1];                 \
                swap32(a0, b0, lane); swap32(a1, b1, lane);                        \
                swap16(a0, b0, lane); swap16(a1, b1, lane);                        \
                union { unsigned int u[4]; short8 s; } cvv;                        \
                cvv.u[0] = a0; cvv.u[1] = a1; cvv.u[2] = b0; cvv.u[3] = b1;        \
                pa[qh][gp] = cvv.s;                                                \
            }                                                                      \
        }                                                                          \
        __builtin_amdgcn_s_setprio(1);                                             \
        _Pragma("unroll")                                                          \
        for (int g = 0; g < 4; g++) {                                              \
            const short8 vb0 = *(const short8*)&SB[(BUF) * 8192 + 4096 + g * 1024 + rdA]; \
            const short8 vb1 = *(const short8*)&SB[(BUF) * 8192 + 4096 + g * 1024 + rdB]; \
            _Pragma("unroll")                                                      \
            for (int qh = 0; qh < 2; qh++) {                                       \
                ctx[qh][g] = __builtin_amdgcn_mfma_f32_16x16x32_bf16(pa[qh][0], vb0, ctx[qh][g], 0, 0, 0); \
                ctx[qh][g] = __builtin_amdgcn_mfma_f32_16x16x32_bf16(pa[qh][1], vb1, ctx[qh][g], 0, 0, 0); \
            }                                                                      \
        }                                                                          \
        _Pragma("unroll")                                                          \
        for (int qh = 0; qh < 2; qh++) {                                           \
            accL[qh] = __builtin_amdgcn_mfma_f32_16x16x32_bf16(pa[qh][0], onesb, accL[qh], 0, 0, 0); \
            accL[qh] = __builtin_amdgcn_mfma_f32_16x16x32_bf16(pa[qh][1], onesb, accL[qh], 0, 0, 0); \
        }                                                                          \
        __builtin_amdgcn_s_setprio(0);                                             \
    } while (0)

    STAGE(0);   // prologue: kv tile 0 -> buf0
#pragma unroll 1
    for (int it = 0; it < 16; it++) {
        __syncthreads();            // buf0 ready (vmcnt drained); buf1 reads done
        STAGE(1);                   // prefetch tile 2*it+1 -> buf1
        COMPUTE(0);                 // tile 2*it from buf0
        __syncthreads();            // buf1 ready; buf0 reads done
        if (it < 15) STAGE(0);      // prefetch tile 2*it+2 -> buf0
        COMPUTE(1);                 // tile 2*it+1 from buf1
    }
#undef STAGE
#undef COMPUTE

    // epilogue: full denominator known -> write ctx/l as bf16 directly
#pragma unroll
    for (int qh = 0; qh < 2; qh++) {
#pragma unroll
        for (int r = 0; r < 4; r++) {
            const float inv = 1.0f / accL[qh][r];
            const int srow = q0w + qh * 16 + qd * 4 + r;
            u16* orow = ctxbf + (size_t)srow * 2048 + hb;
#pragma unroll
            for (int g = 0; g < 4; g++)
                orow[g * 16 + lm] = f2bf(ctx[qh][g][r] * inv);
        }
    }
}

// =====================================================================
// host orchestration (6 launches)
// =====================================================================
extern "C" void kernel_launch(void* const* d_in, const int* in_sizes, int n_in,
                              void* d_out, int out_size, void* d_ws, size_t ws_size,
                              hipStream_t stream) {
    const float* qx = (const float*)d_in[0];
    const float* kx = (const float*)d_in[1];
    const float* vx = (const float*)d_in[2];
    const float* qc = (const float*)d_in[3];
    const float* kc = (const float*)d_in[4];
    const float* W_qx = (const float*)d_in[5];   const float* b_qx = (const float*)d_in[6];
    const float* W_kx = (const float*)d_in[7];   const float* b_kx = (const float*)d_in[8];
    const float* W_vx = (const float*)d_in[9];   const float* b_vx = (const float*)d_in[10];
    const float* W_qc = (const float*)d_in[11];  const float* b_qc = (const float*)d_in[12];
    const float* W_kc = (const float*)d_in[13];  const float* b_kc = (const float*)d_in[14];
    const float* W_out = (const float*)d_in[15]; const float* b_out = (const float*)d_in[16];
    const float* W_Vqx = (const float*)d_in[17]; const float* b_Vqx = (const float*)d_in[18];
    const float* W_Vqc = (const float*)d_in[19]; const float* b_Vqc = (const float*)d_in[20];
    const float* W_Vkx = (const float*)d_in[21]; const float* b_Vkx = (const float*)d_in[22];
    const float* W_Vkc = (const float*)d_in[23]; const float* b_Vkc = (const float*)d_in[24];

    char* ws = (char*)d_ws;
    const size_t MB = 1048576;
    u16* Aq  = (u16*)ws;
    u16* Ak  = (u16*)(ws + 16 * MB);
    u16* Av  = (u16*)(ws + 32 * MB);
    u16* Wtq = (u16*)(ws + 40 * MB);
    u16* Wtk = (u16*)(ws + 44 * MB);
    u16* Wtv = (u16*)(ws + 48 * MB);
    u16* Wto = (u16*)(ws + 50 * MB);
    u16* Pv    = (u16*)(ws + 52 * MB);
    u16* qg    = (u16*)(ws + 60 * MB);
    u16* kg    = (u16*)(ws + 68 * MB);
    u16* ctxbf = (u16*)(ws + 76 * MB);
    float* wfused = (float*)(ws + 84 * MB);                       // 4 x 1024
    float* bdot   = (float*)(ws + 84 * MB + 16384);               // 4 scalars
    float* lam    = (float*)(ws + 84 * MB + 16384 + 256);         // 2 x 4096
    u16* Vtg    = (u16*)(ws + 32 * MB);        // aliases Av (dead after proj)

    // 1. fused gating weight vectors + bias-dot consts
    WFuseJobs wf;
    wf.W[0] = W_qx; wf.wv[0] = W_Vqx; wf.bl[0] = b_qx; wf.out[0] = wfused;
    wf.W[1] = W_qc; wf.wv[1] = W_Vqc; wf.bl[1] = b_qc; wf.out[1] = wfused + 1024;
    wf.W[2] = W_kx; wf.wv[2] = W_Vkx; wf.bl[2] = b_kx; wf.out[2] = wfused + 2048;
    wf.W[3] = W_kc; wf.wv[3] = W_Vkc; wf.bl[3] = b_kc; wf.out[3] = wfused + 3072;
    wf.bdot = bdot;
    wfuse<<<dim3(64, 4), 256, 0, stream>>>(wf);

    // 2. gatewt: lambdas + scaled concat-K bf16 A matrices + v cast
    //    + all 6 weight transposes, one launch.
    GCWJobs gj;
    gj.xa[0] = qx; gj.xc[0] = qc; gj.w1[0] = wfused;        gj.w2[0] = wfused + 1024;
    gj.sA[0] = b_Vqx; gj.sB[0] = b_Vqc; gj.lamout[0] = lam;        gj.dst[0] = Aq;
    gj.xa[1] = kx; gj.xc[1] = kc; gj.w1[1] = wfused + 2048; gj.w2[1] = wfused + 3072;
    gj.sA[1] = b_Vkx; gj.sB[1] = b_Vkc; gj.lamout[1] = lam + 4096; gj.dst[1] = Ak;
    gj.xa[2] = vx; gj.xc[2] = nullptr; gj.w1[2] = nullptr; gj.w2[2] = nullptr;
    gj.sA[2] = nullptr; gj.sB[2] = nullptr; gj.lamout[2] = nullptr; gj.dst[2] = Av;
    gj.bdot = bdot;
    gj.wsrc[0] = W_qx; gj.wdst[0] = Wtq; gj.wstride[0] = 2048; gj.wkoff[0] = 0;
    gj.wsrc[1] = W_qc; gj.wdst[1] = Wtq; gj.wstride[1] = 2048; gj.wkoff[1] = 1024;
    gj.wsrc[2] = W_kx; gj.wdst[2] = Wtk; gj.wstride[2] = 2048; gj.wkoff[2] = 0;
    gj.wsrc[3] = W_kc; gj.wdst[3] = Wtk; gj.wstride[3] = 2048; gj.wkoff[3] = 1024;
    gj.wsrc[4] = W_vx; gj.wdst[4] = Wtv; gj.wstride[4] = 1024; gj.wkoff[4] = 0;
    gj.wsrc[5] = W_out; gj.wdst[5] = Wto; gj.wstride[5] = 1024; gj.wkoff[5] = 0;
    gatewt<<<dim3(1024, 9), 256, 0, stream>>>(gj);

    // 3. projections (projall v5, proven): q (K=2048, pre-scaled),
    //    k (K=2048), v (K=1024). grid (8,32,3) = 768 blocks, 3/CU.
    const float QSCALE = 0.18033688011112042f;   // log2(e)/sqrt(64)
    PJobs pj;
    pj.j[0].A = Aq; pj.j[0].Bt = Wtq; pj.j[0].K = 2048;
    pj.j[0].biasA = b_qx; pj.j[0].biasC = b_qc; pj.j[0].lam = lam;
    pj.j[0].out = qg; pj.j[0].outf = nullptr; pj.j[0].scale = QSCALE;
    pj.j[1].A = Ak; pj.j[1].Bt = Wtk; pj.j[1].K = 2048;
    pj.j[1].biasA = b_kx; pj.j[1].biasC = b_kc; pj.j[1].lam = lam + 4096;
    pj.j[1].out = kg; pj.j[1].outf = nullptr; pj.j[1].scale = 1.0f;
    pj.j[2].A = Av; pj.j[2].Bt = Wtv; pj.j[2].K = 1024;
    pj.j[2].biasA = b_vx; pj.j[2].biasC = nullptr; pj.j[2].lam = nullptr;
    pj.j[2].out = Pv; pj.j[2].outf = nullptr; pj.j[2].scale = 1.0f;
    pj.j[3] = pj.j[2];
    projall<<<dim3(8, 32, 3), 256, 0, stream>>>(pj);

    // 4. transpose V (Av dead -> Vtg aliases it)
    vtrans<<<dim3(64, 2, 32), 256, 0, stream>>>(Pv, Vtg);

    // 5. attention (full KV, 128 q-rows/block, 4 waves x qh=2, direct write)
    attn9<<<dim3(16, 32), 256, 0, stream>>>(qg, kg, Vtg, ctxbf);

    // 6. output projection -> d_out (fp32): 128x64 tiles, 512 blocks
    projout<<<dim3(512), 256, 0, stream>>>(ctxbf, Wto, b_out, (float*)d_out);
}